// Round 6
// baseline (145.877 us; speedup 1.0000x reference)
//
#include <hip/hip_runtime.h>
#include <cstdint>

// Problem dims (fixed by the reference)
#define B_DIM 16
#define T_DIM 1024
#define DK    512     // D_IN
#define H_DIM 1024

// Tiling
#define TCH    128                 // t-rows per block (chunk)
#define NCH    (T_DIM / TCH)       // 8 chunks per (b,strip)
#define NB     128                 // output cols per block
#define NSTRIP (H_DIM / NB)        // 8 strips
#define NKT    16                  // k-tiles of BK=32

typedef __bf16 bf16x8 __attribute__((ext_vector_type(8)));
typedef __bf16 bf16x4 __attribute__((ext_vector_type(4)));
typedef float  f32x4  __attribute__((ext_vector_type(4)));

// ---- async global->LDS (16B per lane, wave-uniform LDS base + lane*16) ----
typedef __attribute__((address_space(1))) unsigned int* as1p;
typedef __attribute__((address_space(3))) unsigned int* as3p;

__device__ __forceinline__ void async_cp16(const void* g, void* l) {
  __builtin_amdgcn_global_load_lds((as1p)(uint64_t)g,
                                   (as3p)(uint32_t)(uint64_t)l, 16, 0, 0);
}

// ---- small prep: W cvt+transpose, meta, flag zero (x is NOT pre-processed) ----
// W: f32 [H][DK] -> bf16 k-major wbT[kq][h][8]
// grid = 512 (W) + 4 (meta) + 512 (flags) = 1028 blocks x 256 thr
__global__ __launch_bounds__(256) void prep(const float* __restrict__ W,
                                            __bf16* __restrict__ wbT,
                                            const float* __restrict__ raw_a,
                                            float4* __restrict__ meta,
                                            unsigned long long* __restrict__ flags) {
  const int bid = blockIdx.x, tid = threadIdx.x;
  if (bid < 512) {                        // W -> wbT[kq][h][8]
    const int i = bid * 256 + tid;        // i < 131072
    const int h  = i >> 7;                // DK/4 = 128 x4-chunks per row
    const int k0 = (i & 127) * 4;
    f32x4 v = ((const f32x4*)W)[i];
    bf16x4 o;
    o.x = (__bf16)v.x; o.y = (__bf16)v.y; o.z = (__bf16)v.z; o.w = (__bf16)v.w;
    *(bf16x4*)(wbT + ((size_t)(k0 >> 3) * H_DIM + h) * 8 + (k0 & 7)) = o;
  } else if (bid < 516) {                 // meta: {a, log2|a|, neg?, zero?}
    const int h = (bid - 512) * 256 + tid;
    const float a = tanhf(raw_a[h]);
    const float la2 = log2f(fabsf(a));
    meta[h] = make_float4(a, la2, (a < 0.f) ? 1.f : 0.f, (fabsf(a) < 1e-6f) ? 1.f : 0.f);
  } else {                                // lookback flags: zero 131072 u64
    flags[(bid - 516) * 256 + tid] = 0ULL;
  }
}

// ---- fused: GEMM (z = x W^T + b) + chunk-parallel weighted-cumsum scan ----
// Reads x DIRECTLY as f32 (no pre-pass): A-tile staged f32 via global_load_lds
// (per-lane global src does the row-major -> k-major shuffle; LDS dest linear),
// converted to bf16 on the ds_read side.  Per row, one BK=32 tile consumes one
// full 128B line of x -> 100% line utilization.
// Grid: 1024 blocks; g = bid&127 (b = g>>3, chunk = g&7), strip = bid>>7 —
// the mapping proven in rounds 1-3.  bid%8 == chunk -> ALL consumers of one
// (b,chunk) x-slice (the 8 strip-blocks, bids chunk + b*8 + strip*128) land on
// XCD (chunk%8): the 256KB f32 slice is read into that XCD's L2 once and
// re-served locally.  Lookback predecessors (lower chunk, same b,strip) are
// within 7 adjacent bids -> dispatch-order safe, co-resident, near-zero spin.
// Block: 256 thr / 4 waves; tile 128x128; wave = (rw: 64 rows, cg: 64 cols).
// Depth-2 global_load_lds pipeline, counted vmcnt (never 0 mid-loop), raw
// s_barrier.  k-major LDS: every 16-lane ds_read phase is 256B contiguous.
__global__ __launch_bounds__(256, 3) void fused_rnn(
    const float* __restrict__ xf,    // [B][T][DK] f32 (raw input)
    const __bf16* __restrict__ wbT,  // [64][H][8] k-major
    const float* __restrict__ bias,  // [H]
    const float4* __restrict__ meta, // [H]
    const float* __restrict__ h0g,   // [B, H]
    unsigned long long* __restrict__ flags, // [B][NSTRIP][NCH][NB] {flag|val}
    float* __restrict__ out) {       // [B*T, H]
  __shared__ __align__(16) float  Asf[2][8][TCH][4];  // 32 KB  f32 [kq4][row][4]
  __shared__ __align__(16) __bf16 Bs[2][4][NB][8];    // 16 KB  bf16 [kq][col][8]
  __shared__ float chunkTot[2][NB];
  __shared__ float colCarry[NB];

  const int tid  = threadIdx.x;
  const int wave = tid >> 6;
  const int lane = tid & 63;
  const int q  = lane >> 4;      // 0..3
  const int c  = lane & 15;      // 0..15
  const int rw = wave & 1;       // row half: rows rw*64..+64
  const int cg = wave >> 1;      // col half: cols cg*64..+64

  const int bid   = blockIdx.x;
  const int g     = bid & 127;
  const int strip = bid >> 7;    // 0..7
  const int b     = g >> 3;
  const int chunk = g & 7;
  const int t0    = chunk * TCH;
  const int n0    = strip * NB;

  // bias only is needed before the k-loop (folded into MFMA C-init);
  // all other per-column constants load after the loop (lower live range).
  float bias_j[4];
#pragma unroll
  for (int j = 0; j < 4; ++j) bias_j[j] = bias[n0 + cg * 64 + j * 16 + c];

  const float* const xB = xf + (size_t)(b * T_DIM + t0) * DK;

  // stage one BK=32 k-tile: A f32 1024 slots (4/thr) + B bf16 512 slots (2/thr)
  // = 6 cp16/thread/tile; vmcnt counts below depend on this
  auto stage = [&](int kt, int buf) {
#pragma unroll
    for (int it = 0; it < 4; ++it) {
      const int s = it * 256 + tid;          // 0..1023
      const int kq4 = s >> 7, row = s & 127; // 16B = 4 f32 of row's k-range
      async_cp16(xB + (size_t)row * DK + kt * 32 + kq4 * 4,
                 &Asf[buf][kq4][row][0]);
    }
#pragma unroll
    for (int it = 0; it < 2; ++it) {
      const int s = it * 256 + tid;
      const int kq = s >> 7, col = s & 127;
      async_cp16(wbT + ((size_t)(kt * 4 + kq) * H_DIM + n0 + col) * 8,
                 &Bs[buf][kq][col][0]);
    }
  };

  // bias folded into the MFMA C-init (all 4 rows of a frag share the column)
  f32x4 acc[4][4];
#pragma unroll
  for (int i = 0; i < 4; ++i)
#pragma unroll
    for (int j = 0; j < 4; ++j)
      acc[i][j] = (f32x4){bias_j[j], bias_j[j], bias_j[j], bias_j[j]};

  // prologue: 2 tiles in flight
  stage(0, 0); stage(1, 1);

  for (int kt = 0; kt < NKT; ++kt) {
    const int buf = kt & 1;
    // wait for tile kt only; tile kt+1's 6 loads stay in flight
    if (kt < NKT - 1) asm volatile("s_waitcnt vmcnt(6)" ::: "memory");
    else              asm volatile("s_waitcnt vmcnt(0)" ::: "memory");
    __builtin_amdgcn_s_barrier();   // tile-kt staged & visible to all waves;
                                    // everyone also done reading buf (kt-2)
    bf16x8 af[4], bfr[4];
#pragma unroll
    for (int i = 0; i < 4; ++i) {
      const int row = rw * 64 + i * 16 + c;
      const f32x4 a0 = *(const f32x4*)(&Asf[buf][2 * q][row][0]);
      const f32x4 a1 = *(const f32x4*)(&Asf[buf][2 * q + 1][row][0]);
      bf16x8 t;
      t[0] = (__bf16)a0.x; t[1] = (__bf16)a0.y; t[2] = (__bf16)a0.z; t[3] = (__bf16)a0.w;
      t[4] = (__bf16)a1.x; t[5] = (__bf16)a1.y; t[6] = (__bf16)a1.z; t[7] = (__bf16)a1.w;
      af[i] = t;
    }
#pragma unroll
    for (int j = 0; j < 4; ++j)
      bfr[j] = *(const bf16x8*)(&Bs[buf][q][cg * 64 + j * 16 + c][0]);
#pragma unroll
    for (int i = 0; i < 4; ++i)
#pragma unroll
      for (int j = 0; j < 4; ++j)
        acc[i][j] = __builtin_amdgcn_mfma_f32_16x16x32_bf16(af[i], bfr[j], acc[i][j], 0, 0, 0);
    __builtin_amdgcn_sched_barrier(0);  // no LDS read may sink past this point
    __builtin_amdgcn_s_barrier();       // all reads of buf done -> restage ok
    if (kt < NKT - 2) stage(kt + 2, buf);
  }

  // per-column constants for the scan (loaded post-loop: short live range)
  float la2_j[4], a_j[4], ai_j[4], sgn_j[4], h0_j[4];
  bool zm_j[4];
#pragma unroll
  for (int j = 0; j < 4; ++j) {
    const int col = n0 + cg * 64 + j * 16 + c;
    const float4 mt = meta[col];
    a_j[j]   = mt.x;
    la2_j[j] = mt.y;
    ai_j[j]  = 1.f / mt.x;              // signed 1/a (inf for a~0: handled)
    sgn_j[j] = (mt.z != 0.f) ? -1.f : 1.f;
    zm_j[j]  = mt.w != 0.f;
    h0_j[j]  = h0g[(size_t)b * H_DIM + col];
  }

  // ---- scan phase 1: per-wave weighted prefix over this wave's 64 rows ----
  // acc[i][j][r] = z (incl. bias) at t = t0+rw*64+i*16+q*4+r, col = n0+cg*64+j*16+c.
  // tp1 = t+1 is ODD at r=0, so sign of a^(t+1) at r=0 is sgn; multiplying by
  // signed 1/a alternates it.  inv = (u<0) ? 1e12 : min(u,1e12) reproduces
  // ref's 1/max(p,1e-12) exactly (incl. a<0 and a~0 cases).
  float base_[4][4];
  float icarry[4] = {0.f, 0.f, 0.f, 0.f};
#pragma unroll
  for (int i = 0; i < 4; ++i) {
    const int tp10 = t0 + rw * 64 + i * 16 + q * 4 + 1;
#pragma unroll
    for (int j = 0; j < 4; ++j) {
      float u = __builtin_amdgcn_exp2f(-la2_j[j] * (float)tp10) * sgn_j[j];
      f32x4 wv;
#pragma unroll
      for (int r = 0; r < 4; ++r) {
        const float uu = fminf(u, 1e12f);
        const float inv = (u < 0.f) ? 1e12f : uu;
        wv[r] = acc[i][j][r] * inv;
        u *= ai_j[j];
      }
      const float pr0 = wv[0];
      const float pr1 = pr0 + wv[1];
      const float pr2 = pr1 + wv[2];
      const float pr3 = pr2 + wv[3];
      const float x1 = __shfl_xor(pr3, 16, 64);   // q^1
      const float x2 = __shfl_xor(pr3, 32, 64);   // q^2
      const float x3 = __shfl_xor(pr3, 48, 64);   // q^3
      float sq = 0.f;
      if (q >= 2) sq += x2 + x3;
      if (q & 1) sq += x1;
      const float base = icarry[j] + sq;
      base_[i][j] = base;
      acc[i][j] = (f32x4){base + pr0, base + pr1, base + pr2, base + pr3};
      icarry[j] += pr3 + x1 + x2 + x3;   // total over this i-group's 16 rows
    }
  }
  if (q == 0) {
#pragma unroll
    for (int j = 0; j < 4; ++j) chunkTot[rw][cg * 64 + j * 16 + c] = icarry[j];
  }
  __syncthreads();

  // ---- publish own chunk total, then decoupled lookback for the carry ----
  if (tid < NB) {
    const int col = tid;
    const size_t fb = ((size_t)b * NSTRIP + strip) * NCH * NB;
    const float tot = chunkTot[0][col] + chunkTot[1][col];
    atomicExch(&flags[fb + (size_t)chunk * NB + col],
               (1ULL << 32) | (unsigned long long)__float_as_uint(tot));
    float s = 0.f;
    for (int p = 0; p < chunk; ++p) {
      unsigned long long v = atomicAdd(&flags[fb + (size_t)p * NB + col], 0ULL);
      while (!(v >> 32)) {
        __builtin_amdgcn_s_sleep(4);
        v = atomicAdd(&flags[fb + (size_t)p * NB + col], 0ULL);
      }
      s += __uint_as_float((unsigned int)v);
    }
    colCarry[col] = s;
  }
  __syncthreads();

  // ---- phase 2: add carry (+h0), produce h = p*(v+h0), write out ----
  float cc_[4];
#pragma unroll
  for (int j = 0; j < 4; ++j) {
    const int colL = cg * 64 + j * 16 + c;
    float s = colCarry[colL];
    if (rw) s += chunkTot[0][colL];
    cc_[j] = s + h0_j[j];
  }
#pragma unroll
  for (int i = 0; i < 4; ++i) {
    const int tp10 = t0 + rw * 64 + i * 16 + q * 4 + 1;
#pragma unroll
    for (int j = 0; j < 4; ++j) {
      float pv = __builtin_amdgcn_exp2f(la2_j[j] * (float)tp10) * sgn_j[j];
      const int col = n0 + cg * 64 + j * 16 + c;
#pragma unroll
      for (int r = 0; r < 4; ++r) {
        const int tl = t0 + rw * 64 + i * 16 + q * 4 + r;
        const float hv = pv * (acc[i][j][r] + cc_[j]);
        // zero-mask path: recover z = w*1e-12 (inv == 1e12 exactly when zm)
        const float wr = acc[i][j][r] - ((r == 0) ? base_[i][j] : acc[i][j][r - 1]);
        out[(size_t)(b * T_DIM + tl) * H_DIM + col] = zm_j[j] ? wr * 1e-12f : hv;
        pv *= a_j[j];
      }
    }
  }
}

extern "C" void kernel_launch(void* const* d_in, const int* in_sizes, int n_in,
                              void* d_out, int out_size, void* d_ws, size_t ws_size,
                              hipStream_t stream) {
  const float* x     = (const float*)d_in[0];  // [B,T,DK]
  const float* h0    = (const float*)d_in[1];  // [B,H]
  const float* raw_a = (const float*)d_in[2];  // [H]
  const float* W     = (const float*)d_in[3];  // [H,DK]
  const float* bias  = (const float*)d_in[4];  // [H]
  float* out = (float*)d_out;                  // [B,T,H]

  char* ws = (char*)d_ws;
  __bf16* wbT = (__bf16*)(ws);                         // 1048576 B
  float4* meta = (float4*)(ws + 1048576);              //   16384 B
  unsigned long long* flags =
      (unsigned long long*)(ws + 1048576 + 16384);     // 1048576 B

  prep<<<1028, 256, 0, stream>>>(W, wbT, raw_a, meta, flags);
  fused_rnn<<<1024, 256, 0, stream>>>(x, wbT, bias, meta, h0, flags, out);
}

// Round 8
// 139.709 us; speedup vs baseline: 1.0442x; 1.0442x over previous
//
#include <hip/hip_runtime.h>
#include <cstdint>

// Problem dims (fixed by the reference)
#define B_DIM 16
#define T_DIM 1024
#define DK    512     // D_IN
#define H_DIM 1024

// Tiling
#define TCH    128                 // t-rows per block (chunk)
#define NCH    (T_DIM / TCH)       // 8 chunks per (b,strip)
#define NB     128                 // output cols per block
#define NSTRIP (H_DIM / NB)        // 8 strips
#define NKT    16                  // k-tiles of BK=32

typedef __bf16 bf16x8 __attribute__((ext_vector_type(8)));
typedef __bf16 bf16x4 __attribute__((ext_vector_type(4)));
typedef float  f32x4  __attribute__((ext_vector_type(4)));

// ---- async global->LDS (16B per lane, wave-uniform LDS base + lane*16) ----
typedef __attribute__((address_space(1))) unsigned int* as1p;
typedef __attribute__((address_space(3))) unsigned int* as3p;

__device__ __forceinline__ void async_cp16(const void* g, void* l) {
  __builtin_amdgcn_global_load_lds((as1p)(uint64_t)g,
                                   (as3p)(uint32_t)(uint64_t)l, 16, 0, 0);
}

// ---- small prep: W cvt+transpose, meta, flag zero (x is NOT pre-processed) ----
// W: f32 [H][DK] -> bf16 k-major wbT[kq][h][8]
// grid = 512 (W) + 4 (meta) + 512 (flags) = 1028 blocks x 256 thr
__global__ __launch_bounds__(256) void prep(const float* __restrict__ W,
                                            __bf16* __restrict__ wbT,
                                            const float* __restrict__ raw_a,
                                            float4* __restrict__ meta,
                                            unsigned long long* __restrict__ flags) {
  const int bid = blockIdx.x, tid = threadIdx.x;
  if (bid < 512) {                        // W -> wbT[kq][h][8]
    const int i = bid * 256 + tid;        // i < 131072
    const int h  = i >> 7;                // DK/4 = 128 x4-chunks per row
    const int k0 = (i & 127) * 4;
    f32x4 v = ((const f32x4*)W)[i];
    bf16x4 o;
    o.x = (__bf16)v.x; o.y = (__bf16)v.y; o.z = (__bf16)v.z; o.w = (__bf16)v.w;
    *(bf16x4*)(wbT + ((size_t)(k0 >> 3) * H_DIM + h) * 8 + (k0 & 7)) = o;
  } else if (bid < 516) {                 // meta: {a, log2|a|, neg?, zero?}
    const int h = (bid - 512) * 256 + tid;
    const float a = tanhf(raw_a[h]);
    const float la2 = log2f(fabsf(a));
    meta[h] = make_float4(a, la2, (a < 0.f) ? 1.f : 0.f, (fabsf(a) < 1e-6f) ? 1.f : 0.f);
  } else {                                // lookback flags: zero 131072 u64
    flags[(bid - 516) * 256 + tid] = 0ULL;
  }
}

// ---- fused: GEMM (z = x W^T + b) + chunk-parallel weighted-cumsum scan ----
// x read DIRECTLY as f32, reg-staged (T14): per tile each thread loads 4x16B
// ROW-CONTIGUOUS f32 (8 lanes = one row's full 128B k-window -> coalesced,
// 100% line use), converts to bf16 OFF the MFMA path, ds_writes into a bf16
// As (8 KB/tile, depth-2).  B (pre-transposed bf16) keeps global_load_lds at
// depth-3.  LDS = 16 + 24 = 40 KB exactly -> 4 blocks/CU (scan scratch is
// aliased into dead As).  Registers are the extra pipeline stage: A loads
// issue ~1.2 iters before their ds_write; B has 2+ iters in flight; counted
// vmcnt (never 0 mid-loop).  MFMA feed: pure bf16 ds_read_b128, 2-way banks.
// Correctness does NOT depend on the counted vmcnt: writeA's register
// dependency on loadA(kt+2) forces an implicit drain of all older VMEM
// (incl. stageB(kt+2)), so B(kt) is settled 2 iterations before its read.
// Grid: 1024 blocks; g = bid&127 (b = g>>3, chunk = g&7), strip = bid>>7 —
// proven mapping: bid%8 == chunk pins each (b,chunk) x-slice to one XCD's L2;
// lookback predecessors are within 7 adjacent bids; at 4 blocks/CU the whole
// 1024-block grid is co-resident -> lookback cannot deadlock under ANY
// dispatch order.
__global__ __launch_bounds__(256, 4) void fused_rnn(
    const float* __restrict__ xf,    // [B][T][DK] f32 (raw input)
    const __bf16* __restrict__ wbT,  // [64][H][8] k-major
    const float* __restrict__ bias,  // [H]
    const float4* __restrict__ meta, // [H]
    const float* __restrict__ h0g,   // [B, H]
    unsigned long long* __restrict__ flags, // [B][NSTRIP][NCH][NB] {flag|val}
    float* __restrict__ out) {       // [B*T, H]
  __shared__ __align__(16) __bf16 As[2][4][TCH][8];  // 16 KB  [buf][kq][row][8]
  __shared__ __align__(16) __bf16 Bs[3][4][NB][8];   // 24 KB  [buf][kq][col][8]
  // scan scratch aliased into As (dead after the k-loop):
  // scr[0..255] = chunkTot[2][NB], scr[256..383] = colCarry[NB]
  float* const scr = (float*)&As[0][0][0][0];

  const int tid  = threadIdx.x;
  const int wave = tid >> 6;
  const int lane = tid & 63;
  const int q  = lane >> 4;      // 0..3
  const int c  = lane & 15;      // 0..15
  const int rw = wave & 1;       // row half: rows rw*64..+64
  const int cg = wave >> 1;      // col half: cols cg*64..+64

  const int bid   = blockIdx.x;
  const int g     = bid & 127;
  const int strip = bid >> 7;    // 0..7
  const int b     = g >> 3;
  const int chunk = g & 7;
  const int t0    = chunk * TCH;
  const int n0    = strip * NB;

  const int t8 = tid >> 3;       // 0..31: row-base for A staging
  const int ck = tid & 7;        // 16B chunk within the row's 128B k-window

  float bias_j[4];
#pragma unroll
  for (int j = 0; j < 4; ++j) bias_j[j] = bias[n0 + cg * 64 + j * 16 + c];

  const float* const xB = xf + (size_t)(b * T_DIM + t0) * DK;

  // ---- A: reg-staged.  loadA(kt): 4x global dwordx4 (coalesced: 8 lanes
  // cover one row's 128B window).  writeA: cvt f32->bf16, 4x ds_write_b64.
  f32x4 ar[4];
  auto loadA = [&](int kt) {
#pragma unroll
    for (int it = 0; it < 4; ++it)
      ar[it] = *(const f32x4*)(xB + (size_t)(it * 32 + t8) * DK + kt * 32 + ck * 4);
  };
  auto writeA = [&](int buf) {
#pragma unroll
    for (int it = 0; it < 4; ++it) {
      bf16x4 o;
      o.x = (__bf16)ar[it].x; o.y = (__bf16)ar[it].y;
      o.z = (__bf16)ar[it].z; o.w = (__bf16)ar[it].w;
      *(bf16x4*)(&As[buf][ck >> 1][it * 32 + t8][(ck & 1) * 4]) = o;
    }
  };
  // ---- B: global_load_lds, 2 cp16/thread/tile (vmcnt ledger counts these)
  auto stageB = [&](int kt, int buf) {
#pragma unroll
    for (int it = 0; it < 2; ++it) {
      const int s = it * 256 + tid;
      const int kq = s >> 7, col = s & 127;
      async_cp16(wbT + ((size_t)(kt * 4 + kq) * H_DIM + n0 + col) * 8,
                 &Bs[buf][kq][col][0]);
    }
  };

  // bias folded into the MFMA C-init
  f32x4 acc[4][4];
#pragma unroll
  for (int i = 0; i < 4; ++i)
#pragma unroll
    for (int j = 0; j < 4; ++j)
      acc[i][j] = (f32x4){bias_j[j], bias_j[j], bias_j[j], bias_j[j]};

  // prologue: B tiles 0..2 in flight; A tiles 0,1 written to LDS; A tile 2 in regs
  loadA(0);
  stageB(0, 0); stageB(1, 1); stageB(2, 2);
  writeA(0);          // compiler waits A(0) loads here
  loadA(1);
  writeA(1);          // waits A(1); also drains B(0..2) (older) — harmless
  loadA(2);           // consumed at kt=0

  for (int kt = 0; kt < NKT; ++kt) {
    const int bufA = kt & 1, bufB = kt % 3;
    // B(kt) is guaranteed drained by the compiler's A-reg waits (B is older);
    // counted vmcnt is insurance: steady-state outstanding <= 6.
    if (kt < NKT - 2) asm volatile("s_waitcnt vmcnt(6)" ::: "memory");
    else              asm volatile("s_waitcnt vmcnt(0)" ::: "memory");
    asm volatile("s_waitcnt lgkmcnt(0)" ::: "memory");  // our ds_writes drained
    __builtin_amdgcn_s_barrier();   // tile kt fully staged & visible

    bf16x8 af[4], bfr[4];
#pragma unroll
    for (int i = 0; i < 4; ++i)
      af[i] = *(const bf16x8*)(&As[bufA][q][rw * 64 + i * 16 + c][0]);
#pragma unroll
    for (int j = 0; j < 4; ++j)
      bfr[j] = *(const bf16x8*)(&Bs[bufB][q][cg * 64 + j * 16 + c][0]);
#pragma unroll
    for (int i = 0; i < 4; ++i)
#pragma unroll
      for (int j = 0; j < 4; ++j)
        acc[i][j] = __builtin_amdgcn_mfma_f32_16x16x32_bf16(af[i], bfr[j], acc[i][j], 0, 0, 0);
    __builtin_amdgcn_sched_barrier(0);  // no LDS read may sink past this point
    __builtin_amdgcn_s_barrier();       // As[bufA], Bs[bufB] free
    __builtin_amdgcn_sched_barrier(0);  // no restage op may hoist above
    if (kt + 3 < NKT) stageB(kt + 3, bufB);   // (a) B prefetch, 2+ iters slack
    if (kt + 2 < NKT) writeA(bufA);           // (b) cvt+write A(kt+2) from regs
    if (kt + 3 < NKT) loadA(kt + 3);          // (c) issue next A loads
  }

  // per-column constants for the scan (loaded post-loop: short live range)
  float la2_j[4], a_j[4], ai_j[4], sgn_j[4], h0_j[4];
  bool zm_j[4];
#pragma unroll
  for (int j = 0; j < 4; ++j) {
    const int col = n0 + cg * 64 + j * 16 + c;
    const float4 mt = meta[col];
    a_j[j]   = mt.x;
    la2_j[j] = mt.y;
    ai_j[j]  = 1.f / mt.x;              // signed 1/a (inf for a~0: handled)
    sgn_j[j] = (mt.z != 0.f) ? -1.f : 1.f;
    zm_j[j]  = mt.w != 0.f;
    h0_j[j]  = h0g[(size_t)b * H_DIM + col];
  }

  // ---- scan phase 1: per-wave weighted prefix over this wave's 64 rows ----
  // acc[i][j][r] = z (incl. bias) at t = t0+rw*64+i*16+q*4+r, col = n0+cg*64+j*16+c.
  // tp1 = t+1 is ODD at r=0, so sign of a^(t+1) at r=0 is sgn; multiplying by
  // signed 1/a alternates it.  inv = (u<0) ? 1e12 : min(u,1e12) reproduces
  // ref's 1/max(p,1e-12) exactly (incl. a<0 and a~0 cases).
  float base_[4][4];
  float icarry[4] = {0.f, 0.f, 0.f, 0.f};
#pragma unroll
  for (int i = 0; i < 4; ++i) {
    const int tp10 = t0 + rw * 64 + i * 16 + q * 4 + 1;
#pragma unroll
    for (int j = 0; j < 4; ++j) {
      float u = __builtin_amdgcn_exp2f(-la2_j[j] * (float)tp10) * sgn_j[j];
      f32x4 wv;
#pragma unroll
      for (int r = 0; r < 4; ++r) {
        const float uu = fminf(u, 1e12f);
        const float inv = (u < 0.f) ? 1e12f : uu;
        wv[r] = acc[i][j][r] * inv;
        u *= ai_j[j];
      }
      const float pr0 = wv[0];
      const float pr1 = pr0 + wv[1];
      const float pr2 = pr1 + wv[2];
      const float pr3 = pr2 + wv[3];
      const float x1 = __shfl_xor(pr3, 16, 64);   // q^1
      const float x2 = __shfl_xor(pr3, 32, 64);   // q^2
      const float x3 = __shfl_xor(pr3, 48, 64);   // q^3
      float sq = 0.f;
      if (q >= 2) sq += x2 + x3;
      if (q & 1) sq += x1;
      const float base = icarry[j] + sq;
      base_[i][j] = base;
      acc[i][j] = (f32x4){base + pr0, base + pr1, base + pr2, base + pr3};
      icarry[j] += pr3 + x1 + x2 + x3;   // total over this i-group's 16 rows
    }
  }
  if (q == 0) {
#pragma unroll
    for (int j = 0; j < 4; ++j) scr[rw * NB + cg * 64 + j * 16 + c] = icarry[j];
  }
  __syncthreads();

  // ---- publish own chunk total, then decoupled lookback for the carry ----
  if (tid < NB) {
    const int col = tid;
    const size_t fb = ((size_t)b * NSTRIP + strip) * NCH * NB;
    const float tot = scr[col] + scr[NB + col];
    atomicExch(&flags[fb + (size_t)chunk * NB + col],
               (1ULL << 32) | (unsigned long long)__float_as_uint(tot));
    float s = 0.f;
    for (int p = 0; p < chunk; ++p) {
      unsigned long long v = atomicAdd(&flags[fb + (size_t)p * NB + col], 0ULL);
      while (!(v >> 32)) {
        __builtin_amdgcn_s_sleep(4);
        v = atomicAdd(&flags[fb + (size_t)p * NB + col], 0ULL);
      }
      s += __uint_as_float((unsigned int)v);
    }
    scr[2 * NB + col] = s;
  }
  __syncthreads();

  // ---- phase 2: add carry (+h0), produce h = p*(v+h0), write out ----
  float cc_[4];
#pragma unroll
  for (int j = 0; j < 4; ++j) {
    const int colL = cg * 64 + j * 16 + c;
    float s = scr[2 * NB + colL];
    if (rw) s += scr[colL];
    cc_[j] = s + h0_j[j];
  }
#pragma unroll
  for (int i = 0; i < 4; ++i) {
    const int tp10 = t0 + rw * 64 + i * 16 + q * 4 + 1;
#pragma unroll
    for (int j = 0; j < 4; ++j) {
      float pv = __builtin_amdgcn_exp2f(la2_j[j] * (float)tp10) * sgn_j[j];
      const int col = n0 + cg * 64 + j * 16 + c;
#pragma unroll
      for (int r = 0; r < 4; ++r) {
        const int tl = t0 + rw * 64 + i * 16 + q * 4 + r;
        const float hv = pv * (acc[i][j][r] + cc_[j]);
        // zero-mask path: recover z = w*1e-12 (inv == 1e12 exactly when zm)
        const float wr = acc[i][j][r] - ((r == 0) ? base_[i][j] : acc[i][j][r - 1]);
        out[(size_t)(b * T_DIM + tl) * H_DIM + col] = zm_j[j] ? wr * 1e-12f : hv;
        pv *= a_j[j];
      }
    }
  }
}

extern "C" void kernel_launch(void* const* d_in, const int* in_sizes, int n_in,
                              void* d_out, int out_size, void* d_ws, size_t ws_size,
                              hipStream_t stream) {
  const float* x     = (const float*)d_in[0];  // [B,T,DK]
  const float* h0    = (const float*)d_in[1];  // [B,H]
  const float* raw_a = (const float*)d_in[2];  // [H]
  const float* W     = (const float*)d_in[3];  // [H,DK]
  const float* bias  = (const float*)d_in[4];  // [H]
  float* out = (float*)d_out;                  // [B,T,H]

  char* ws = (char*)d_ws;
  __bf16* wbT = (__bf16*)(ws);                         // 1048576 B
  float4* meta = (float4*)(ws + 1048576);              //   16384 B
  unsigned long long* flags =
      (unsigned long long*)(ws + 1048576 + 16384);     // 1048576 B

  prep<<<1028, 256, 0, stream>>>(W, wbT, raw_a, meta, flags);
  fused_rnn<<<1024, 256, 0, stream>>>(x, wbT, bias, meta, h0, flags, out);
}

// Round 9
// 137.211 us; speedup vs baseline: 1.0632x; 1.0182x over previous
//
#include <hip/hip_runtime.h>
#include <cstdint>

// Problem dims (fixed by the reference)
#define B_DIM 16
#define T_DIM 1024
#define DK    512     // D_IN
#define H_DIM 1024

// Tiling
#define TCH    128                 // t-rows per block (chunk)
#define NCH    (T_DIM / TCH)       // 8 chunks per (b,strip)
#define NB     128                 // output cols per block
#define NSTRIP (H_DIM / NB)        // 8 strips
#define NKT    16                  // k-tiles of BK=32

typedef __bf16 bf16x8 __attribute__((ext_vector_type(8)));
typedef __bf16 bf16x4 __attribute__((ext_vector_type(4)));
typedef float  f32x4  __attribute__((ext_vector_type(4)));

// ---- async global->LDS (16B per lane, wave-uniform LDS base + lane*16) ----
typedef __attribute__((address_space(1))) unsigned int* as1p;
typedef __attribute__((address_space(3))) unsigned int* as3p;

__device__ __forceinline__ void async_cp16(const void* g, void* l) {
  __builtin_amdgcn_global_load_lds((as1p)(uint64_t)g,
                                   (as3p)(uint32_t)(uint64_t)l, 16, 0, 0);
}

// ---- merged prep (round-3 proven) ----
// x: f32 [B][T][DK] -> bf16 k-major xbt[b][kq=0..63][t=0..1023][8]
// W: f32 [H][DK]    -> bf16 k-major wbT[kq][h][8]
// meta: {a, log2|a|, neg?, zero?} per h;  flags: zeroed lookback array.
// grid = 4096 (x) + 512 (W) + 4 (meta) + 512 (flags) = 5124 blocks x 256 thr
__global__ __launch_bounds__(256) void prep(const float* __restrict__ x,
                                            __bf16* __restrict__ xbt,
                                            const float* __restrict__ W,
                                            __bf16* __restrict__ wbT,
                                            const float* __restrict__ raw_a,
                                            float4* __restrict__ meta,
                                            unsigned long long* __restrict__ flags) {
  const int bid = blockIdx.x, tid = threadIdx.x;
  if (bid < 4096) {                       // x transpose + cvt, 8 elems/thread
    const int g = bid * 256 + tid;        // < 1048576
    const int b = g >> 16;
    const int r = g & 65535;
    // 4 lanes share a 128B x-row segment (coalesced reads);
    // 16 lanes of one kq write 256B contiguous in xbt (coalesced writes).
    const int kq = ((r >> 12) << 2) | (tid & 3);                // 0..63
    const int t  = (((r >> 6) & 63) << 4) | ((tid & 63) >> 2);  // 0..1023
    const float* src = x + ((size_t)(b * T_DIM + t) * DK + kq * 8);
    f32x4 v0 = ((const f32x4*)src)[0];
    f32x4 v1 = ((const f32x4*)src)[1];
    bf16x8 o;
    o[0] = (__bf16)v0.x; o[1] = (__bf16)v0.y; o[2] = (__bf16)v0.z; o[3] = (__bf16)v0.w;
    o[4] = (__bf16)v1.x; o[5] = (__bf16)v1.y; o[6] = (__bf16)v1.z; o[7] = (__bf16)v1.w;
    *(bf16x8*)(xbt + ((size_t)(b * 64 + kq) * T_DIM + t) * 8) = o;
  } else if (bid < 4608) {                // W -> wbT[kq][h][8]
    const int i = (bid - 4096) * 256 + tid;   // i < 131072
    const int h  = i >> 7;                // DK/4 = 128 x4-chunks per row
    const int k0 = (i & 127) * 4;
    f32x4 v = ((const f32x4*)W)[i];
    bf16x4 o;
    o.x = (__bf16)v.x; o.y = (__bf16)v.y; o.z = (__bf16)v.z; o.w = (__bf16)v.w;
    *(bf16x4*)(wbT + ((size_t)(k0 >> 3) * H_DIM + h) * 8 + (k0 & 7)) = o;
  } else if (bid < 4612) {                // meta
    const int h = (bid - 4608) * 256 + tid;
    const float a = tanhf(raw_a[h]);
    const float la2 = log2f(fabsf(a));
    meta[h] = make_float4(a, la2, (a < 0.f) ? 1.f : 0.f, (fabsf(a) < 1e-6f) ? 1.f : 0.f);
  } else {                                // lookback flags: zero 131072 u64
    flags[(bid - 4612) * 256 + tid] = 0ULL;
  }
}

// ---- fused: GEMM (z = x W^T + b) + chunk-parallel weighted-cumsum scan ----
// A (xbt, k-major bf16) loads DIRECTLY global->VGPR: lane (q,c) reads 16B at
// xbt[b][kt*4+q][t0+row]; each 16-lane group = 256B contiguous (coalesced),
// panel is XCD-L2-resident.  A is double-buffered in registers (afA/afB via
// 2-unrolled loop -> static indexing).  Only B lives in LDS: depth-4
// global_load_lds (32 KB), staged kt+3 AFTER the barrier (lands in last
// iter's read buffer - the barrier guarantees all waves consumed it, since
// passing barrier@kt implies MFMA@kt-1 done which lgkm-waited its ds_reads).
// ONE barrier per kt.  Counted vmcnt 8/6/4 = #ops provably issued after
// B(kt); any extra VM ops (e.g. spills) only make the wait stricter.
// Grid: 1024 blocks; g = bid&127 (b = g>>3, chunk = g&7), strip = bid>>7 —
// proven mapping: bid%8 == chunk pins each (b,chunk) A-panel to one XCD L2;
// lookback predecessors within 7 adjacent bids; 4 blocks/CU -> whole grid
// co-resident -> lookback deadlock-free under any dispatch order.
__global__ __launch_bounds__(256, 4) void fused_rnn(
    const __bf16* __restrict__ xbt,  // [B][64][T][8] k-major
    const __bf16* __restrict__ wbT,  // [64][H][8]   k-major
    const float* __restrict__ bias,  // [H]
    const float4* __restrict__ meta, // [H]
    const float* __restrict__ h0g,   // [B, H]
    unsigned long long* __restrict__ flags, // [B][NSTRIP][NCH][NB] {flag|val}
    float* __restrict__ out) {       // [B*T, H]
  __shared__ __align__(16) __bf16 Bs[4][4][NB][8];   // 32 KB [buf][kq][col][8]
  // scan scratch aliased into Bs[0] (dead after the k-loop):
  // scr[0..255] = chunkTot[2][NB], scr[256..383] = colCarry[NB]
  float* const scr = (float*)&Bs[0][0][0][0];

  const int tid  = threadIdx.x;
  const int wave = tid >> 6;
  const int lane = tid & 63;
  const int q  = lane >> 4;      // 0..3
  const int c  = lane & 15;      // 0..15
  const int rw = wave & 1;       // row half: rows rw*64..+64
  const int cg = wave >> 1;      // col half: cols cg*64..+64

  const int bid   = blockIdx.x;
  const int g     = bid & 127;
  const int strip = bid >> 7;    // 0..7
  const int b     = g >> 3;
  const int chunk = g & 7;
  const int t0    = chunk * TCH;
  const int n0    = strip * NB;

  float bias_j[4];
#pragma unroll
  for (int j = 0; j < 4; ++j) bias_j[j] = bias[n0 + cg * 64 + j * 16 + c];

  // per-lane A base: row = t0 + rw*64 + c (+ i*16), kq-plane = b*64 + q (+ kt*4)
  const __bf16* const xA =
      xbt + ((size_t)(b * 64 + q) * T_DIM + t0 + rw * 64 + c) * 8;
  // per kt: +4 kq-planes = 4*T_DIM*8 = 32768 elems; per i: +16 rows = 128 elems

  auto stageB = [&](int kt) {
    const int buf = kt & 3;
#pragma unroll
    for (int it = 0; it < 2; ++it) {
      const int s = it * 256 + tid;
      const int kq = s >> 7, col = s & 127;
      async_cp16(wbT + ((size_t)(kt * 4 + kq) * H_DIM + n0 + col) * 8,
                 &Bs[buf][kq][col][0]);
    }
  };

  // bias folded into the MFMA C-init
  f32x4 acc[4][4];
#pragma unroll
  for (int i = 0; i < 4; ++i)
#pragma unroll
    for (int j = 0; j < 4; ++j)
      acc[i][j] = (f32x4){bias_j[j], bias_j[j], bias_j[j], bias_j[j]};

  bf16x8 afA[4], afB[4];

  // prologue: B tiles 0..2 staged; A(0) -> afA
  stageB(0); stageB(1); stageB(2);
#pragma unroll
  for (int i = 0; i < 4; ++i) afA[i] = *(const bf16x8*)(xA + i * 128);

  // one barrier per kt; A reg-double-buffered; B depth-4
  auto body = [&](int kt, bf16x8 (&cur)[4], bf16x8 (&nxt)[4]) {
    const int buf = kt & 3;
    if (kt <= NKT - 3)      asm volatile("s_waitcnt vmcnt(8)" ::: "memory");
    else if (kt == NKT - 2) asm volatile("s_waitcnt vmcnt(6)" ::: "memory");
    else                    asm volatile("s_waitcnt vmcnt(4)" ::: "memory");
    __builtin_amdgcn_s_barrier();        // B(kt) visible; all waves consumed
    __builtin_amdgcn_sched_barrier(0);   //   buf (kt-1)&3 -> restage is safe
    if (kt + 3 < NKT) stageB(kt + 3);    // writes buf (kt-1)&3
    if (kt + 1 < NKT) {
      const __bf16* p = xA + (size_t)(kt + 1) * 32768;
#pragma unroll
      for (int i = 0; i < 4; ++i) nxt[i] = *(const bf16x8*)(p + i * 128);
    }
    bf16x8 b0 = *(const bf16x8*)(&Bs[buf][q][cg * 64 + 0 * 16 + c][0]);
    bf16x8 b1 = *(const bf16x8*)(&Bs[buf][q][cg * 64 + 1 * 16 + c][0]);
#pragma unroll
    for (int i = 0; i < 4; ++i) {
      acc[i][0] = __builtin_amdgcn_mfma_f32_16x16x32_bf16(cur[i], b0, acc[i][0], 0, 0, 0);
      acc[i][1] = __builtin_amdgcn_mfma_f32_16x16x32_bf16(cur[i], b1, acc[i][1], 0, 0, 0);
    }
    bf16x8 b2 = *(const bf16x8*)(&Bs[buf][q][cg * 64 + 2 * 16 + c][0]);
    bf16x8 b3 = *(const bf16x8*)(&Bs[buf][q][cg * 64 + 3 * 16 + c][0]);
#pragma unroll
    for (int i = 0; i < 4; ++i) {
      acc[i][2] = __builtin_amdgcn_mfma_f32_16x16x32_bf16(cur[i], b2, acc[i][2], 0, 0, 0);
      acc[i][3] = __builtin_amdgcn_mfma_f32_16x16x32_bf16(cur[i], b3, acc[i][3], 0, 0, 0);
    }
  };
  for (int kt2 = 0; kt2 < NKT; kt2 += 2) {   // static A-buffer alternation
    body(kt2,     afA, afB);
    body(kt2 + 1, afB, afA);
  }

  // per-column constants for the scan (loaded post-loop: short live range)
  float la2_j[4], a_j[4], ai_j[4], sgn_j[4], h0_j[4];
  bool zm_j[4];
#pragma unroll
  for (int j = 0; j < 4; ++j) {
    const int col = n0 + cg * 64 + j * 16 + c;
    const float4 mt = meta[col];
    a_j[j]   = mt.x;
    la2_j[j] = mt.y;
    ai_j[j]  = 1.f / mt.x;              // signed 1/a (inf for a~0: handled)
    sgn_j[j] = (mt.z != 0.f) ? -1.f : 1.f;
    zm_j[j]  = mt.w != 0.f;
    h0_j[j]  = h0g[(size_t)b * H_DIM + col];
  }

  // ---- scan phase 1: per-wave weighted prefix over this wave's 64 rows ----
  // acc[i][j][r] = z (incl. bias) at t = t0+rw*64+i*16+q*4+r, col = n0+cg*64+j*16+c.
  // tp1 = t+1 is ODD at r=0, so sign of a^(t+1) at r=0 is sgn; multiplying by
  // signed 1/a alternates it.  inv = (u<0) ? 1e12 : min(u,1e12) reproduces
  // ref's 1/max(p,1e-12) exactly (incl. a<0 and a~0 cases).
  float base_[4][4];
  float icarry[4] = {0.f, 0.f, 0.f, 0.f};
#pragma unroll
  for (int i = 0; i < 4; ++i) {
    const int tp10 = t0 + rw * 64 + i * 16 + q * 4 + 1;
#pragma unroll
    for (int j = 0; j < 4; ++j) {
      float u = __builtin_amdgcn_exp2f(-la2_j[j] * (float)tp10) * sgn_j[j];
      f32x4 wv;
#pragma unroll
      for (int r = 0; r < 4; ++r) {
        const float uu = fminf(u, 1e12f);
        const float inv = (u < 0.f) ? 1e12f : uu;
        wv[r] = acc[i][j][r] * inv;
        u *= ai_j[j];
      }
      const float pr0 = wv[0];
      const float pr1 = pr0 + wv[1];
      const float pr2 = pr1 + wv[2];
      const float pr3 = pr2 + wv[3];
      const float x1 = __shfl_xor(pr3, 16, 64);   // q^1
      const float x2 = __shfl_xor(pr3, 32, 64);   // q^2
      const float x3 = __shfl_xor(pr3, 48, 64);   // q^3
      float sq = 0.f;
      if (q >= 2) sq += x2 + x3;
      if (q & 1) sq += x1;
      const float base = icarry[j] + sq;
      base_[i][j] = base;
      acc[i][j] = (f32x4){base + pr0, base + pr1, base + pr2, base + pr3};
      icarry[j] += pr3 + x1 + x2 + x3;   // total over this i-group's 16 rows
    }
  }
  if (q == 0) {
#pragma unroll
    for (int j = 0; j < 4; ++j) scr[rw * NB + cg * 64 + j * 16 + c] = icarry[j];
  }
  __syncthreads();

  // ---- publish own chunk total, then decoupled lookback for the carry ----
  if (tid < NB) {
    const int col = tid;
    const size_t fb = ((size_t)b * NSTRIP + strip) * NCH * NB;
    const float tot = scr[col] + scr[NB + col];
    atomicExch(&flags[fb + (size_t)chunk * NB + col],
               (1ULL << 32) | (unsigned long long)__float_as_uint(tot));
    float s = 0.f;
    for (int p = 0; p < chunk; ++p) {
      unsigned long long v = atomicAdd(&flags[fb + (size_t)p * NB + col], 0ULL);
      while (!(v >> 32)) {
        __builtin_amdgcn_s_sleep(8);
        v = atomicAdd(&flags[fb + (size_t)p * NB + col], 0ULL);
      }
      s += __uint_as_float((unsigned int)v);
    }
    scr[2 * NB + col] = s;
  }
  __syncthreads();

  // ---- phase 2: add carry (+h0), produce h = p*(v+h0), write out ----
  float cc_[4];
#pragma unroll
  for (int j = 0; j < 4; ++j) {
    const int colL = cg * 64 + j * 16 + c;
    float s = scr[2 * NB + colL];
    if (rw) s += scr[colL];
    cc_[j] = s + h0_j[j];
  }
#pragma unroll
  for (int i = 0; i < 4; ++i) {
    const int tp10 = t0 + rw * 64 + i * 16 + q * 4 + 1;
#pragma unroll
    for (int j = 0; j < 4; ++j) {
      float pv = __builtin_amdgcn_exp2f(la2_j[j] * (float)tp10) * sgn_j[j];
      const int col = n0 + cg * 64 + j * 16 + c;
#pragma unroll
      for (int r = 0; r < 4; ++r) {
        const int tl = t0 + rw * 64 + i * 16 + q * 4 + r;
        const float hv = pv * (acc[i][j][r] + cc_[j]);
        // zero-mask path: recover z = w*1e-12 (inv == 1e12 exactly when zm)
        const float wr = acc[i][j][r] - ((r == 0) ? base_[i][j] : acc[i][j][r - 1]);
        out[(size_t)(b * T_DIM + tl) * H_DIM + col] = zm_j[j] ? wr * 1e-12f : hv;
        pv *= a_j[j];
      }
    }
  }
}

extern "C" void kernel_launch(void* const* d_in, const int* in_sizes, int n_in,
                              void* d_out, int out_size, void* d_ws, size_t ws_size,
                              hipStream_t stream) {
  const float* x     = (const float*)d_in[0];  // [B,T,DK]
  const float* h0    = (const float*)d_in[1];  // [B,H]
  const float* raw_a = (const float*)d_in[2];  // [H]
  const float* W     = (const float*)d_in[3];  // [H,DK]
  const float* bias  = (const float*)d_in[4];  // [H]
  float* out = (float*)d_out;                  // [B,T,H]

  char* ws = (char*)d_ws;
  __bf16* xbt = (__bf16*)(ws);                               // 16777216 B
  __bf16* wbT = (__bf16*)(ws + 16777216);                    //  1048576 B
  float4* meta = (float4*)(ws + 16777216 + 1048576);         //    16384 B
  unsigned long long* flags =
      (unsigned long long*)(ws + 16777216 + 1048576 + 16384); // 1048576 B

  prep<<<5124, 256, 0, stream>>>(x, xbt, W, wbT, raw_a, meta, flags);
  fused_rnn<<<1024, 256, 0, stream>>>(xbt, wbT, bias, meta, h0, flags, out);
}